// Round 10
// baseline (3843.560 us; speedup 1.0000x reference)
//
#include <hip/hip_runtime.h>

constexpr int N = 20000;
constexpr int E = 320000;
constexpr int Bc = 2;
constexpr int L = 25;
constexpr float EPS = 1e-5f;

typedef __attribute__((ext_vector_type(8))) short short8;
typedef __attribute__((ext_vector_type(4))) float f32x4;
typedef __attribute__((ext_vector_type(4))) unsigned short u16x4;

__device__ __forceinline__ unsigned short f2bf(float f) {
  unsigned u = __float_as_uint(f);
  u += 0x7fff + ((u >> 16) & 1);   // RNE
  return (unsigned short)(u >> 16);
}

__device__ __forceinline__ int sel5(int i, int a0, int a1, int a2, int a3, int a4) {
  int r = a4;
  r = (i == 3) ? a3 : r;
  r = (i == 2) ? a2 : r;
  r = (i == 1) ? a1 : r;
  r = (i == 0) ? a0 : r;
  return r;
}

// ---------------- CSR build (once per launch; edges shared by both graphs) ----------------
__global__ void hist_kernel(const int* __restrict__ row, int* __restrict__ deg) {
  int e = blockIdx.x * blockDim.x + threadIdx.x;
  if (e < E) atomicAdd(&deg[row[e]], 1);
}

__global__ __launch_bounds__(1024) void scan_kernel(const int* __restrict__ deg,
                                                    int* __restrict__ row_start,
                                                    int* __restrict__ cursor) {
  __shared__ int s[1024];
  const int t = threadIdx.x;
  constexpr int CH = (N + 1023) / 1024;
  int base = t * CH;
  int sum = 0;
  for (int k = 0; k < CH; ++k) {
    int idx = base + k;
    if (idx < N) sum += deg[idx];
  }
  s[t] = sum;
  __syncthreads();
  for (int off = 1; off < 1024; off <<= 1) {
    int v = (t >= off) ? s[t - off] : 0;
    __syncthreads();
    s[t] += v;
    __syncthreads();
  }
  int excl = s[t] - sum;
  for (int k = 0; k < CH; ++k) {
    int idx = base + k;
    if (idx < N) {
      row_start[idx] = excl;
      cursor[idx] = excl;
      excl += deg[idx];
    }
  }
  if (t == 1023) row_start[N] = s[1023];
}

__global__ void scatter_kernel(const int* __restrict__ row, int* __restrict__ cursor,
                               int* __restrict__ edge_order) {
  int e = blockIdx.x * blockDim.x + threadIdx.x;
  if (e < E) {
    int p = atomicAdd(&cursor[row[e]], 1);
    edge_order[p] = e;
  }
}

__global__ void sortmap_kernel(const int* __restrict__ edge_order,
                               const int* __restrict__ col,
                               const float* __restrict__ eattr,
                               int* __restrict__ col_s, float2* __restrict__ ea_s) {
  int p = blockIdx.x * blockDim.x + threadIdx.x;
  if (p < E) {
    int eid = edge_order[p];
    col_s[p] = col[eid];
    ea_s[p] = *(const float2*)&eattr[2 * (size_t)eid];
  }
}

// ---------------- weight pre-pack: bf16 MFMA A-fragments (W^T), once ----------------
// per layer: frags 0..19 = W1ext^T (K=160: w1 rows 0..129, b1 at 130), f = nt*5+ks
//            frags 20..31 = W2ext^T (K=96: w2 rows 0..63, b2 at 64), f2 = nt*3+ks
//            frags 32..51 = UWext^T (K=160: uw rows 0..127, ub at 128), f3 = nt*5+ks
__global__ __launch_bounds__(512) void pack_kernel(
    const float* __restrict__ msg_w1, const float* __restrict__ msg_b1,
    const float* __restrict__ msg_w2, const float* __restrict__ msg_b2,
    const float* __restrict__ up_w, const float* __restrict__ up_b,
    unsigned short* __restrict__ wpack) {
  const int f = blockIdx.x;   // 0..51
  const int l = blockIdx.y;   // 0..L-1
  const int t = threadIdx.x;  // 0..511
  const int ln = t >> 3, i = t & 7;
  float v = 0.f;
  if (f < 20) {
    int nt = f / 5, ks = f % 5;
    int k = ks * 32 + (ln >> 4) * 8 + i, m = nt * 16 + (ln & 15);
    if (k < 130)       v = msg_w1[(size_t)l * 130 * 64 + (size_t)k * 64 + m];
    else if (k == 130) v = msg_b1[l * 64 + m];
  } else if (f < 32) {
    int f2 = f - 20, nt = f2 / 3, ks = f2 % 3;
    int k = ks * 32 + (ln >> 4) * 8 + i, m = nt * 16 + (ln & 15);
    if (k < 64)        v = msg_w2[(size_t)l * 64 * 64 + (size_t)k * 64 + m];
    else if (k == 64)  v = msg_b2[l * 64 + m];
  } else {
    int f3 = f - 32, nt = f3 / 5, ks = f3 % 5;
    int k = ks * 32 + (ln >> 4) * 8 + i, m = nt * 16 + (ln & 15);
    if (k < 128)       v = up_w[(size_t)l * 128 * 64 + (size_t)k * 64 + m];
    else if (k == 128) v = up_b[l * 64 + m];
  }
  wpack[((size_t)l * 52 + f) * 512 + ln * 8 + i] = f2bf(v);
}

// ---------------- encoder ----------------
__global__ __launch_bounds__(512) void encoder_kernel(
    const float* __restrict__ x, const float* __restrict__ enc_w,
    const float* __restrict__ enc_b, float* __restrict__ h,
    unsigned short* __restrict__ hbf) {
  int idx = blockIdx.x * blockDim.x + threadIdx.x;
  if (idx >= Bc * N * 64) return;
  int j = idx & 63;
  int bn = idx >> 6;
  const float* xp = x + (size_t)bn * 3;
  float v = enc_b[j] + xp[0] * enc_w[j] + xp[1] * enc_w[64 + j] + xp[2] * enc_w[128 + j];
  h[idx] = v;
  hbf[idx] = f2bf(v);
}

// ---------------- fused layer kernel (swapped-operand MFMA) ----------------
constexpr int GPN = 4;
constexpr int GPG = N / GPN;    // 5000
constexpr int NGRP = GPG * Bc;  // 10000
constexpr int EWB = 4;
constexpr int ETPB = 256;

__global__ __launch_bounds__(ETPB, 4) void layer_kernel(
    const unsigned short* __restrict__ hbf_old, unsigned short* __restrict__ hbf_new,
    float* __restrict__ h,
    const int* __restrict__ col_s, const float2* __restrict__ ea_s,
    const int* __restrict__ row_start,
    const unsigned short* __restrict__ wpack_l,
    const float* __restrict__ g1, const float* __restrict__ be1,
    const float* __restrict__ ug, const float* __restrict__ ube) {
  __shared__ __align__(16) unsigned short w1f[20 * 512];  // 20 KB W1^T frags
  __shared__ __align__(16) float pwb[EWB][1280];          // per-wave trans(1024)+aggs(256)

  const int tid = threadIdx.x, lane = tid & 63, w = tid >> 6;
  const int cl = lane & 15, hg = lane >> 4;

  {
    const uint4* src = (const uint4*)wpack_l;
    uint4* dst = (uint4*)w1f;
    for (int idx = tid; idx < 1280; idx += ETPB) dst[idx] = src[idx];
  }
  __syncthreads();  // only block barrier

  const short8* w1v = (const short8*)w1f;
  const short8* gw2 = (const short8*)(wpack_l + 20 * 512);
  const short8* guw = (const short8*)(wpack_l + 32 * 512);

  // per-lane LN constants: channels nt*16 + hg*4 + r
  f32x4 g1c[4], be1c[4];
#pragma unroll
  for (int nt = 0; nt < 4; ++nt) {
    g1c[nt]  = *(const f32x4*)&g1[nt * 16 + hg * 4];
    be1c[nt] = *(const f32x4*)&be1[nt * 16 + hg * 4];
  }

  const int gw = __builtin_amdgcn_readfirstlane(blockIdx.x * EWB + w);
  const int g = (gw >= GPG) ? 1 : 0;
  const int nb = (gw - g * GPG) * GPN;
  const unsigned short* hb = hbf_old + (size_t)g * N * 64;

  const int R0 = row_start[nb],     R1 = row_start[nb + 1], R2 = row_start[nb + 2],
            R3 = row_start[nb + 3], R4 = row_start[nb + 4];

  char* transB = (char*)&pwb[w][0];
  char* aggsB  = (char*)&pwb[w][1024];

  // zero psum staging (covers deg-0 nodes)
#pragma unroll
  for (int k = 0; k < 4; ++k)
    *(float*)(aggsB + k * 256 + ((lane * 4) ^ ((k & 3) << 4))) = 0.f;

  f32x4 psum[4];
#pragma unroll
  for (int nt = 0; nt < 4; ++nt) psum[nt] = (f32x4){0.f, 0.f, 0.f, 0.f};

  auto finalize = [&](int k) {
#pragma unroll
    for (int nt = 0; nt < 4; ++nt)
      *(f32x4*)(transB + cl * 256 + ((nt * 64 + hg * 16) ^ ((cl & 7) << 4))) = psum[nt];
    float tot = 0.f;
#pragma unroll
    for (int e = 0; e < 16; ++e)
      tot += *(const float*)(transB + e * 256 + ((lane * 4) ^ ((e & 7) << 4)));
    *(float*)(aggsB + k * 256 + ((lane * 4) ^ ((k & 3) << 4))) = tot;
#pragma unroll
    for (int nt = 0; nt < 4; ++nt) psum[nt] = (f32x4){0.f, 0.f, 0.f, 0.f};
  };

  // ================= edge phase: flat pipelined tile loop =================
  int kC = 0;
  while (kC < 4 && sel5(kC + 1, R0, R1, R2, R3, R4) == sel5(kC, R0, R1, R2, R3, R4)) ++kC;
  bool valid = (kC < 4);
  int tsC = 0, eeC = 0;
  short8 b2C, b3C; float2 eaC = {0.f, 0.f};
  if (valid) {
    tsC = sel5(kC, R0, R1, R2, R3, R4);
    eeC = sel5(kC + 1, R0, R1, R2, R3, R4);
    int p = tsC + cl; if (p >= eeC) p = eeC - 1;
    const unsigned short* pc = hb + (((size_t)col_s[p]) << 6) + hg * 8;
    b2C = *(const short8*)pc;
    b3C = *(const short8*)(pc + 32);
    eaC = ea_s[p];
  }

  int curk = -1;
  f32x4 acc0[4];

  while (valid) {
    // advance + prefetch next tile
    int kN = kC, tsN = tsC + 16, eeN = eeC;
    bool validN = true;
    if (tsN >= eeC) {
      kN = kC + 1;
      while (kN < 4 && sel5(kN + 1, R0, R1, R2, R3, R4) == sel5(kN, R0, R1, R2, R3, R4)) ++kN;
      if (kN < 4) {
        tsN = sel5(kN, R0, R1, R2, R3, R4);
        eeN = sel5(kN + 1, R0, R1, R2, R3, R4);
      } else validN = false;
    }
    short8 b2N, b3N; float2 eaN = {0.f, 0.f};
    if (validN) {
      int p = tsN + cl; if (p >= eeN) p = eeN - 1;
      const unsigned short* pc = hb + (((size_t)col_s[p]) << 6) + hg * 8;
      b2N = *(const short8*)pc;
      b3N = *(const short8*)(pc + 32);
      eaN = ea_s[p];
    }

    // node entry: finalize prev, compute acc0 = W1^T(ks0,1) x h_row (8 MFMA)
    if (curk != kC) {
      if (curk >= 0) finalize(curk);
      curk = kC;
      const unsigned short* pn = hb + (((size_t)(nb + kC)) << 6) + hg * 8;
      short8 av0 = *(const short8*)pn;
      short8 av1 = *(const short8*)(pn + 32);
#pragma unroll
      for (int nt = 0; nt < 4; ++nt) {
        short8 A0 = w1v[(nt * 5 + 0) * 64 + lane];
        short8 A1 = w1v[(nt * 5 + 1) * 64 + lane];
        f32x4 t = __builtin_amdgcn_mfma_f32_16x16x32_bf16(A0, av0, (f32x4){0.f,0.f,0.f,0.f}, 0, 0, 0);
        acc0[nt] = __builtin_amdgcn_mfma_f32_16x16x32_bf16(A1, av1, t, 0, 0, 0);
      }
    }

    // ea B-frag: k 128..159 = [ea.x, ea.y, 1, 0...]
    short8 eaB = (short8){0, 0, 0, 0, 0, 0, 0, 0};
    if (hg == 0) {
      eaB[0] = (short)f2bf(eaC.x);
      eaB[1] = (short)f2bf(eaC.y);
      eaB[2] = (short)0x3F80;
    }

    // GEMV1 per tile: 12 MFMA, acc0 as C-in
    f32x4 vv[4];
#pragma unroll
    for (int nt = 0; nt < 4; ++nt) {
      short8 A2 = w1v[(nt * 5 + 2) * 64 + lane];
      short8 A3 = w1v[(nt * 5 + 3) * 64 + lane];
      short8 A4 = w1v[(nt * 5 + 4) * 64 + lane];
      f32x4 t = __builtin_amdgcn_mfma_f32_16x16x32_bf16(A2, b2C, acc0[nt], 0, 0, 0);
      t = __builtin_amdgcn_mfma_f32_16x16x32_bf16(A3, b3C, t, 0, 0, 0);
      vv[nt] = __builtin_amdgcn_mfma_f32_16x16x32_bf16(A4, eaB, t, 0, 0, 0);
    }

    // LN per edge (lane owns 16 channels of edge cl): in-lane + 4 shfl
    float s = 0.f, q = 0.f;
#pragma unroll
    for (int nt = 0; nt < 4; ++nt) {
#pragma unroll
      for (int r = 0; r < 4; ++r) {
        s += vv[nt][r];
        q = fmaf(vv[nt][r], vv[nt][r], q);
      }
    }
    s += __shfl_xor(s, 16, 64); s += __shfl_xor(s, 32, 64);
    q += __shfl_xor(q, 16, 64); q += __shfl_xor(q, 32, 64);
    float mu = s * 0.015625f;
    float var = fmaf(-mu, mu, q * 0.015625f);
    float rsq = rsqrtf(var + EPS);
#pragma unroll
    for (int nt = 0; nt < 4; ++nt) {
#pragma unroll
      for (int r = 0; r < 4; ++r) {
        float gm = g1c[nt][r] * rsq;
        vv[nt][r] = fmaxf(fmaf(vv[nt][r] - mu, gm, be1c[nt][r]), 0.f);
      }
    }

    // psum accumulate (masked by edge validity)
    if (tsC + cl < eeC) {
#pragma unroll
      for (int nt = 0; nt < 4; ++nt) psum[nt] += vv[nt];
    }

    kC = kN; tsC = tsN; eeC = eeN; valid = validN;
    b2C = b2N; b3C = b3N; eaC = eaN;
  }
  if (curk >= 0) finalize(curk);

  // ================= wave-end: GEMV2 + node update (nodes as columns) =================
  const int n3 = (cl < 4) ? cl : 3;

  // B-frags: psum (f32 -> bf16) + deg slot
  short8 pB0, pB1;
#pragma unroll
  for (int ks = 0; ks < 2; ++ks) {
    int x = ks * 128 + hg * 32;
    int key = (n3 & 3) << 4;
    f32x4 qa = *(const f32x4*)(aggsB + n3 * 256 + (x ^ key));
    f32x4 qb = *(const f32x4*)(aggsB + n3 * 256 + ((x + 16) ^ key));
    short8 sb;
    sb[0] = (short)f2bf(qa[0]); sb[1] = (short)f2bf(qa[1]);
    sb[2] = (short)f2bf(qa[2]); sb[3] = (short)f2bf(qa[3]);
    sb[4] = (short)f2bf(qb[0]); sb[5] = (short)f2bf(qb[1]);
    sb[6] = (short)f2bf(qb[2]); sb[7] = (short)f2bf(qb[3]);
    if (ks == 0) pB0 = sb; else pB1 = sb;
  }
  float degf = 0.f;
  if (cl == 0) degf = (float)(R1 - R0);
  else if (cl == 1) degf = (float)(R2 - R1);
  else if (cl == 2) degf = (float)(R3 - R2);
  else if (cl == 3) degf = (float)(R4 - R3);
  short8 degB = (short8){0, 0, 0, 0, 0, 0, 0, 0};
  if (hg == 0) degB[0] = (short)f2bf(degf);

  // GEMV2: aggr = W2ext^T [psum | deg]  (12 MFMA, A-frags from L2-hot prepack)
  f32x4 agg[4];
#pragma unroll
  for (int nt = 0; nt < 4; ++nt) {
    short8 A0 = gw2[(nt * 3 + 0) * 64 + lane];
    short8 A1 = gw2[(nt * 3 + 1) * 64 + lane];
    short8 A2 = gw2[(nt * 3 + 2) * 64 + lane];
    f32x4 t = __builtin_amdgcn_mfma_f32_16x16x32_bf16(A0, pB0, (f32x4){0.f,0.f,0.f,0.f}, 0, 0, 0);
    t = __builtin_amdgcn_mfma_f32_16x16x32_bf16(A1, pB1, t, 0, 0, 0);
    agg[nt] = __builtin_amdgcn_mfma_f32_16x16x32_bf16(A2, degB, t, 0, 0, 0);
  }

  // stage aggr f32 for u-GEMV B-frags (transpose via LDS, keyed by node&3)
  if (cl < 4) {
#pragma unroll
    for (int nt = 0; nt < 4; ++nt)
      *(f32x4*)(transB + cl * 256 + ((nt * 64 + hg * 16) ^ ((cl & 3) << 4))) = agg[nt];
  }

  // u-GEMV B-frags: [h(bf16) | aggr | 1]
  short8 uB0, uB1, uB2, uB3, uB4;
  {
    const unsigned short* pn = hb + (((size_t)(nb + n3)) << 6) + hg * 8;
    uB0 = *(const short8*)pn;
    uB1 = *(const short8*)(pn + 32);
#pragma unroll
    for (int ks = 0; ks < 2; ++ks) {
      int x = ks * 128 + hg * 32;
      int key = (n3 & 3) << 4;
      f32x4 qa = *(const f32x4*)(transB + n3 * 256 + (x ^ key));
      f32x4 qb = *(const f32x4*)(transB + n3 * 256 + ((x + 16) ^ key));
      short8 sb;
      sb[0] = (short)f2bf(qa[0]); sb[1] = (short)f2bf(qa[1]);
      sb[2] = (short)f2bf(qa[2]); sb[3] = (short)f2bf(qa[3]);
      sb[4] = (short)f2bf(qb[0]); sb[5] = (short)f2bf(qb[1]);
      sb[6] = (short)f2bf(qb[2]); sb[7] = (short)f2bf(qb[3]);
      if (ks == 0) uB2 = sb; else uB3 = sb;
    }
    uB4 = (short8){0, 0, 0, 0, 0, 0, 0, 0};
    if (hg == 0) uB4[0] = (short)0x3F80;
  }

  // u-GEMV: 20 MFMA
  f32x4 uacc[4];
#pragma unroll
  for (int nt = 0; nt < 4; ++nt) {
    f32x4 t = __builtin_amdgcn_mfma_f32_16x16x32_bf16(guw[(nt * 5 + 0) * 64 + lane], uB0, (f32x4){0.f,0.f,0.f,0.f}, 0, 0, 0);
    t = __builtin_amdgcn_mfma_f32_16x16x32_bf16(guw[(nt * 5 + 1) * 64 + lane], uB1, t, 0, 0, 0);
    t = __builtin_amdgcn_mfma_f32_16x16x32_bf16(guw[(nt * 5 + 2) * 64 + lane], uB2, t, 0, 0, 0);
    t = __builtin_amdgcn_mfma_f32_16x16x32_bf16(guw[(nt * 5 + 3) * 64 + lane], uB3, t, 0, 0, 0);
    uacc[nt] = __builtin_amdgcn_mfma_f32_16x16x32_bf16(guw[(nt * 5 + 4) * 64 + lane], uB4, t, 0, 0, 0);
  }

  // node LN + relu + residual + store
  float s = 0.f, q = 0.f;
#pragma unroll
  for (int nt = 0; nt < 4; ++nt) {
#pragma unroll
    for (int r = 0; r < 4; ++r) {
      s += uacc[nt][r];
      q = fmaf(uacc[nt][r], uacc[nt][r], q);
    }
  }
  s += __shfl_xor(s, 16, 64); s += __shfl_xor(s, 32, 64);
  q += __shfl_xor(q, 16, 64); q += __shfl_xor(q, 32, 64);
  float mu = s * 0.015625f;
  float var = fmaf(-mu, mu, q * 0.015625f);
  float rsq = rsqrtf(var + EPS);

  if (cl < 4) {
    const size_t gn = ((size_t)(g * N + nb + cl)) << 6;
#pragma unroll
    for (int nt = 0; nt < 4; ++nt) {
      f32x4 ugc  = *(const f32x4*)&ug[nt * 16 + hg * 4];
      f32x4 ubec = *(const f32x4*)&ube[nt * 16 + hg * 4];
      f32x4 hv = *(const f32x4*)&h[gn + nt * 16 + hg * 4];
      u16x4 hb4;
#pragma unroll
      for (int r = 0; r < 4; ++r) {
        float uu = fmaxf(fmaf(uacc[nt][r] - mu, ugc[r] * rsq, ubec[r]), 0.f);
        float nv = hv[r] + uu;
        hv[r] = nv;
        hb4[r] = f2bf(nv);
      }
      *(f32x4*)&h[gn + nt * 16 + hg * 4] = hv;
      *(u16x4*)&hbf_new[gn + nt * 16 + hg * 4] = hb4;
    }
  }
}

// ---------------- decoder ----------------
__global__ __launch_bounds__(512) void decoder_kernel(
    const float* __restrict__ h,
    const float* __restrict__ dw1, const float* __restrict__ db1,
    const float* __restrict__ dw2, const float* __restrict__ db2,
    float* __restrict__ out) {
  __shared__ __align__(16) float w1s[64 * 32];
  __shared__ float w2s[64];
  __shared__ float b1s[32];
  __shared__ float hs[8][64];
  const int tid = threadIdx.x;
  const int lane = tid & 63;
  const int w = tid >> 6;

  for (int idx = tid; idx < 64 * 32; idx += 512) w1s[idx] = dw1[idx];
  if (tid < 64) w2s[tid] = dw2[tid];
  if (tid < 32) b1s[tid] = db1[tid];
  const float ob0 = db2[0], ob1 = db2[1];
  __syncthreads();

  const int total = Bc * N;
  const int per_iter = gridDim.x * 8;
  const int niter = (total + per_iter - 1) / per_iter;
  const int wave_global = blockIdx.x * 8 + w;

  for (int it = 0; it < niter; ++it) {
    const int i = it * per_iter + wave_global;
    if (i < total) {
      hs[w][lane] = h[((size_t)i << 6) + lane];
      float s1 = 0.f;
      if (lane < 32) {
        s1 = b1s[lane];
        for (int k = 0; k < 64; ++k) s1 = fmaf(hs[w][k], w1s[k * 32 + lane], s1);
        s1 = fmaxf(s1, 0.f);
      }
      float c0 = (lane < 32) ? s1 * w2s[lane * 2]     : 0.f;
      float c1 = (lane < 32) ? s1 * w2s[lane * 2 + 1] : 0.f;
#pragma unroll
      for (int off = 16; off > 0; off >>= 1) {
        c0 += __shfl_xor(c0, off, 64);
        c1 += __shfl_xor(c1, off, 64);
      }
      if (lane == 0) {
        out[(size_t)i * 2]     = c0 + ob0;
        out[(size_t)i * 2 + 1] = c1 + ob1;
      }
    }
  }
}

extern "C" void kernel_launch(void* const* d_in, const int* in_sizes, int n_in,
                              void* d_out, int out_size, void* d_ws, size_t ws_size,
                              hipStream_t stream) {
  const float* x        = (const float*)d_in[0];
  const int*   ei       = (const int*)d_in[1];
  const float* eattr    = (const float*)d_in[2];
  const float* enc_w    = (const float*)d_in[3];
  const float* enc_b    = (const float*)d_in[4];
  const float* msg_w1   = (const float*)d_in[5];
  const float* msg_b1   = (const float*)d_in[6];
  const float* msg_ln_g = (const float*)d_in[7];
  const float* msg_ln_b = (const float*)d_in[8];
  const float* msg_w2   = (const float*)d_in[9];
  const float* msg_b2   = (const float*)d_in[10];
  const float* up_w     = (const float*)d_in[11];
  const float* up_b     = (const float*)d_in[12];
  const float* up_ln_g  = (const float*)d_in[13];
  const float* up_ln_b  = (const float*)d_in[14];
  const float* dw1      = (const float*)d_in[15];
  const float* db1      = (const float*)d_in[16];
  const float* dw2      = (const float*)d_in[17];
  const float* db2      = (const float*)d_in[18];
  float* out = (float*)d_out;

  float* h             = (float*)d_ws;                                   // 10.24 MB
  unsigned short* hbf0 = (unsigned short*)(h + (size_t)Bc * N * 64);     // 5.12 MB
  unsigned short* hbf1 = hbf0 + (size_t)Bc * N * 64;                     // 5.12 MB
  unsigned short* wpack = hbf1 + (size_t)Bc * N * 64;                    // 1.33 MB
  float2* ea_sv        = (float2*)(wpack + (size_t)L * 52 * 512);
  int* col_sv          = (int*)(ea_sv + E);
  int* edge_order      = col_sv + E;
  int* deg             = edge_order + E;
  int* row_start       = deg + N;
  int* cursor          = row_start + N + 1;

  const int* row = ei;
  const int* col = ei + E;

  hipMemsetAsync(deg, 0, N * sizeof(int), stream);
  hist_kernel<<<(E + 255) / 256, 256, 0, stream>>>(row, deg);
  scan_kernel<<<1, 1024, 0, stream>>>(deg, row_start, cursor);
  scatter_kernel<<<(E + 255) / 256, 256, 0, stream>>>(row, cursor, edge_order);
  sortmap_kernel<<<(E + 255) / 256, 256, 0, stream>>>(edge_order, col, eattr, col_sv, ea_sv);
  pack_kernel<<<dim3(52, L), 512, 0, stream>>>(msg_w1, msg_b1, msg_w2, msg_b2,
                                               up_w, up_b, wpack);
  encoder_kernel<<<(Bc * N * 64 + 511) / 512, 512, 0, stream>>>(x, enc_w, enc_b, h, hbf0);

  unsigned short* hbufs[2] = {hbf0, hbf1};
  for (int l = 0; l < L; ++l) {
    layer_kernel<<<NGRP / EWB, ETPB, 0, stream>>>(
        hbufs[l & 1], hbufs[(l + 1) & 1], h,
        col_sv, ea_sv, row_start,
        wpack + (size_t)l * 52 * 512,
        msg_ln_g + l * 64, msg_ln_b + l * 64,
        up_ln_g + l * 64, up_ln_b + l * 64);
  }

  decoder_kernel<<<512, 512, 0, stream>>>(h, dw1, db1, dw2, db2, out);
}